// Round 2
// baseline (414.520 us; speedup 1.0000x reference)
//
#include <hip/hip_runtime.h>
#include <hip/hip_bf16.h>

#define B_    16
#define N_    640
#define C_    640
#define H_    8
#define D_    80
#define DP_   96          // padded head dim (3 x 32)
#define CP_   768         // H_*DP_
#define NSEL_ 2048
#define NTOK_ 10240       // B_*N_
#define NKV_  12288       // NTOK_+NSEL_

typedef short bf16x8 __attribute__((ext_vector_type(8)));
typedef float f32x4  __attribute__((ext_vector_type(4)));
typedef unsigned short u16;
typedef unsigned int   u32;

#define MFMA16(a,b,c) __builtin_amdgcn_mfma_f32_16x16x32_bf16((a),(b),(c),0,0,0)

// f32 -> bf16 round-to-nearest-even (finite inputs)
static __device__ __forceinline__ u16 f2b(float f) {
  u32 x = __builtin_bit_cast(u32, f);
  x += 0x7fffu + ((x >> 16) & 1u);
  return (u16)(x >> 16);
}

// async global->LDS, 16B per lane
static __device__ __forceinline__ void gl16(const void* g, void* l) {
  __builtin_amdgcn_global_load_lds((const __attribute__((address_space(1))) u32*)g,
                                   (__attribute__((address_space(3))) u32*)l, 16, 0, 0);
}

// ---------------- convert x (f32 -> bf16), 4 elems/thread ----------------
__global__ __launch_bounds__(256) void k_convert_x(const float* __restrict__ x,
                                                   u16* __restrict__ xb) {
  int i = blockIdx.x * 256 + threadIdx.x;        // 1,638,400 threads
  float4 v = ((const float4*)x)[i];
  ushort4 o;
  o.x = f2b(v.x); o.y = f2b(v.y); o.z = f2b(v.z); o.w = f2b(v.w);
  ((ushort4*)xb)[i] = o;
}

// ---------------- convert W (f32 -> bf16 transposed) ----------------
__global__ __launch_bounds__(256) void k_convert_w(const float* w0, const float* w1,
                                                   const float* w2, const float* w3,
                                                   u16* t0, u16* t1, u16* t2, u16* t3) {
  const float* W = (blockIdx.z == 0) ? w0 : (blockIdx.z == 1) ? w1 : (blockIdx.z == 2) ? w2 : w3;
  u16*         T = (blockIdx.z == 0) ? t0 : (blockIdx.z == 1) ? t1 : (blockIdx.z == 2) ? t2 : t3;
  __shared__ float tile[32][33];
  int tx = threadIdx.x & 31, ty = threadIdx.x >> 5;   // 32 x 8
  int n0 = blockIdx.x * 32, k0 = blockIdx.y * 32;
#pragma unroll
  for (int r = 0; r < 4; r++)
    tile[ty + 8 * r][tx] = W[(k0 + ty + 8 * r) * C_ + n0 + tx];
  __syncthreads();
#pragma unroll
  for (int r = 0; r < 4; r++)
    T[(n0 + ty + 8 * r) * C_ + k0 + tx] = f2b(tile[tx][ty + 8 * r]);
}

// ---------------- zero the head-pad columns of Qp / Kp ----------------
__global__ __launch_bounds__(256) void k_padzero(u16* __restrict__ Qp, u16* __restrict__ Kp) {
  int i = blockIdx.x * 256 + threadIdx.x;   // 163840 jobs = 20480 rows * 8 heads
  int row = i >> 3, h = i & 7;
  u16* p = ((row < NTOK_) ? (Qp + row * CP_) : (Kp + (row - NTOK_) * CP_)) + h * DP_ + D_;
  uint4 z = {0u, 0u, 0u, 0u};
  *(uint4*)(p)     = z;
  *(uint4*)(p + 8) = z;
}

// ---------------- mask -> sel indices (order-preserving) ----------------
__global__ __launch_bounds__(1024) void k_scan(const float* __restrict__ mask,
                                               int* __restrict__ sel) {
  __shared__ int wcnt[16];
  __shared__ int carry;
  int tid = threadIdx.x, lane = tid & 63, wid = tid >> 6;
  float v[10];
#pragma unroll
  for (int r = 0; r < 10; r++) v[r] = mask[r * 1024 + tid];
  if (tid == 0) carry = 0;
  __syncthreads();
  for (int r = 0; r < 10; r++) {
    bool p = v[r] > 0.5f;
    unsigned long long b = __ballot(p);
    if (lane == 0) wcnt[wid] = __popcll(b);
    __syncthreads();
    int off = carry;
    for (int w = 0; w < wid; w++) off += wcnt[w];
    if (p) sel[off + __popcll(b & ((1ull << lane) - 1ull))] = r * 1024 + tid;
    __syncthreads();
    if (tid == 0) {
      int s = 0;
      for (int w = 0; w < 16; w++) s += wcnt[w];
      carry += s;
    }
    __syncthreads();
  }
}

// ---------------- GEMM: C[M,N] = A[M,640] * BT[N,640]^T ----------------
// MODE 0: Q -> Qp padded, scaled by log2e/sqrt(80)
// MODE 1: K -> Kp padded
// MODE 2: V -> Vt transposed [c][token]
// MODE 3: O -> f32 d_out + bias
#define QSCALE_ (1.4426950408889634f * 0.11180339887498949f)

template <int MODE>
__global__ __launch_bounds__(256) void k_gemm(const u16* __restrict__ A,
                                              const u16* __restrict__ BT,
                                              void* __restrict__ out,
                                              const float* __restrict__ bias) {
  __shared__ u16 lA[128 * 32];
  __shared__ u16 lB[128 * 32];
  int tid = threadIdx.x, lane = tid & 63, wid = tid >> 6;
  int l15 = lane & 15, l4 = lane >> 4;
  int m0 = blockIdx.x * 128, n0 = blockIdx.y * 128;
  int wr = wid >> 1, wc = wid & 1;
  int tok = tid >> 2, ch = tid & 3;
  int sc = ch ^ (tok & 3);                 // pre-swizzled source chunk (tok&3 == (tok+64)&3)
  f32x4 acc[4][4];
#pragma unroll
  for (int mi = 0; mi < 4; mi++)
#pragma unroll
    for (int ni = 0; ni < 4; ni++) acc[mi][ni] = (f32x4){0.f, 0.f, 0.f, 0.f};

  for (int k0 = 0; k0 < C_; k0 += 32) {
    __syncthreads();
    gl16(A  + (m0 + tok)      * C_ + k0 + sc * 8, (char*)lA + tid * 16);
    gl16(A  + (m0 + tok + 64) * C_ + k0 + sc * 8, (char*)lA + 4096 + tid * 16);
    gl16(BT + (n0 + tok)      * C_ + k0 + sc * 8, (char*)lB + tid * 16);
    gl16(BT + (n0 + tok + 64) * C_ + k0 + sc * 8, (char*)lB + 4096 + tid * 16);
    __syncthreads();
    bf16x8 af[4], bfr[4];
#pragma unroll
    for (int mi = 0; mi < 4; mi++) {
      int r = wr * 64 + mi * 16 + l15;
      af[mi] = *(const bf16x8*)((const char*)lA + r * 64 + ((l4 ^ (r & 3)) * 16));
    }
#pragma unroll
    for (int ni = 0; ni < 4; ni++) {
      int r = wc * 64 + ni * 16 + l15;
      bfr[ni] = *(const bf16x8*)((const char*)lB + r * 64 + ((l4 ^ (r & 3)) * 16));
    }
#pragma unroll
    for (int mi = 0; mi < 4; mi++)
#pragma unroll
      for (int ni = 0; ni < 4; ni++) acc[mi][ni] = MFMA16(af[mi], bfr[ni], acc[mi][ni]);
  }

  int cbase = n0 + wc * 64, rbase = m0 + wr * 64;
  if (MODE == 0 || MODE == 1) {
    u16* P = (u16*)out;
#pragma unroll
    for (int mi = 0; mi < 4; mi++)
#pragma unroll
      for (int ni = 0; ni < 4; ni++) {
        int c = cbase + ni * 16 + l15;
        int h = c / 80, d = c % 80;
#pragma unroll
        for (int rg = 0; rg < 4; rg++) {
          int r = rbase + mi * 16 + l4 * 4 + rg;
          float v = acc[mi][ni][rg];
          if (MODE == 0) v *= QSCALE_;
          P[r * CP_ + h * DP_ + d] = f2b(v);
        }
      }
  } else if (MODE == 2) {
    u16* P = (u16*)out;
#pragma unroll
    for (int mi = 0; mi < 4; mi++)
#pragma unroll
      for (int ni = 0; ni < 4; ni++) {
        int c = cbase + ni * 16 + l15;
        int r0 = rbase + mi * 16 + l4 * 4;
        ushort4 pk;
        pk.x = f2b(acc[mi][ni][0]); pk.y = f2b(acc[mi][ni][1]);
        pk.z = f2b(acc[mi][ni][2]); pk.w = f2b(acc[mi][ni][3]);
        *(ushort4*)(P + c * NKV_ + r0) = pk;
      }
  } else {
    float* P = (float*)out;
#pragma unroll
    for (int ni = 0; ni < 4; ni++) {
      int c = cbase + ni * 16 + l15;
      float bv = bias[c];
#pragma unroll
      for (int mi = 0; mi < 4; mi++)
#pragma unroll
        for (int rg = 0; rg < 4; rg++)
          P[(rbase + mi * 16 + l4 * 4 + rg) * C_ + c] = acc[mi][ni][rg] + bv;
    }
  }
}

// ---------------- gather sel rows into Kp, sel cols into Vt ----------------
__global__ __launch_bounds__(256) void k_gather(const int* __restrict__ sel,
                                                u16* __restrict__ Kp,
                                                u16* __restrict__ Vt) {
  int i = blockIdx.x;            // 0..2047
  int t = threadIdx.x;
  int s = sel[i];
  const u32* src = (const u32*)(Kp + s * CP_);
  u32* dst = (u32*)(Kp + (NTOK_ + i) * CP_);
  dst[t] = src[t];
  if (t < 128) dst[256 + t] = src[256 + t];
  for (int c = t; c < C_; c += 256)
    Vt[c * NKV_ + NTOK_ + i] = Vt[c * NKV_ + s];
}

// ---------------- flash attention ----------------
// grid (5 qtiles, 8 heads, 16 frames), 4 waves x 32 q-rows, KV tile = 64
__global__ __launch_bounds__(256) void k_attn(const u16* __restrict__ Qp,
                                              const u16* __restrict__ Kp,
                                              const u16* __restrict__ Vt,
                                              u16* __restrict__ Ob) {
  __shared__ u16 kls[64 * DP_];    // [64 tok][96 d]  192B rows, 12 chunks (XOR within 4-groups)
  __shared__ u16 vls[D_ * 64];     // [80 d][64 tok]  128B rows, 8 chunks (full XOR)
  __shared__ u16 pls[4 * 32 * 64]; // per-wave P [32 q][64 k], 128B rows swizzled
  int tid = threadIdx.x, lane = tid & 63, wid = tid >> 6;
  int l15 = lane & 15, l4 = lane >> 4;
  int b = blockIdx.z, h = blockIdx.y, q0 = blockIdx.x * 128 + wid * 32;

  // Q fragments (pre-scaled in Qp)
  bf16x8 qf[2][3];
#pragma unroll
  for (int m = 0; m < 2; m++)
#pragma unroll
    for (int kk = 0; kk < 3; kk++)
      qf[m][kk] = *(const bf16x8*)(Qp + (b * N_ + q0 + m * 16 + l15) * CP_ + h * DP_ + kk * 32 + l4 * 8);

  f32x4 o[2][5];
#pragma unroll
  for (int m = 0; m < 2; m++)
#pragma unroll
    for (int d5 = 0; d5 < 5; d5++) o[m][d5] = (f32x4){0.f, 0.f, 0.f, 0.f};
  float mi_[2][4], li_[2][4];
#pragma unroll
  for (int m = 0; m < 2; m++)
#pragma unroll
    for (int rg = 0; rg < 4; rg++) { mi_[m][rg] = -1e30f; li_[m][rg] = 0.f; }

  // staging maps (constant per thread)
  int i0 = tid, i1 = tid + 256, i2 = tid + 512;
  int kt0 = i0 / 12, kc0 = i0 % 12, ks0 = (kc0 & ~3) | ((kc0 & 3) ^ (kt0 & 3));
  int kt1 = i1 / 12, kc1 = i1 % 12, ks1 = (kc1 & ~3) | ((kc1 & 3) ^ (kt1 & 3));
  int kt2 = i2 / 12, kc2 = i2 % 12, ks2 = (kc2 & ~3) | ((kc2 & 3) ^ (kt2 & 3));
  int vd0 = i0 >> 3, vs0 = (i0 & 7) ^ (vd0 & 7);
  int vd1 = i1 >> 3, vs1 = (i1 & 7) ^ (vd1 & 7);
  int vd2 = i2 >> 3, vs2 = (i2 & 7) ^ (vd2 & 7);
  u16* pw = pls + wid * 2048;

  for (int t = 0; t < 42; t++) {
    int tokbase = (t < 10) ? (b * N_ + t * 64) : (NTOK_ + (t - 10) * 64);
    __syncthreads();
    gl16(Kp + (tokbase + kt0) * CP_ + h * DP_ + ks0 * 8, (char*)kls + i0 * 16);
    gl16(Kp + (tokbase + kt1) * CP_ + h * DP_ + ks1 * 8, (char*)kls + i1 * 16);
    gl16(Kp + (tokbase + kt2) * CP_ + h * DP_ + ks2 * 8, (char*)kls + i2 * 16);
    gl16(Vt + (h * D_ + vd0) * NKV_ + tokbase + vs0 * 8, (char*)vls + i0 * 16);
    gl16(Vt + (h * D_ + vd1) * NKV_ + tokbase + vs1 * 8, (char*)vls + i1 * 16);
    if (tid < 128)
      gl16(Vt + (h * D_ + vd2) * NKV_ + tokbase + vs2 * 8, (char*)vls + i2 * 16);
    __syncthreads();

    // QK^T : S[32 q][64 k]
    f32x4 s[2][4];
#pragma unroll
    for (int m = 0; m < 2; m++)
#pragma unroll
      for (int nt = 0; nt < 4; nt++) s[m][nt] = (f32x4){0.f, 0.f, 0.f, 0.f};
#pragma unroll
    for (int kk = 0; kk < 3; kk++)
#pragma unroll
      for (int nt = 0; nt < 4; nt++) {
        int tk = nt * 16 + l15;
        bf16x8 kb = *(const bf16x8*)((const char*)kls + tk * 192 + (kk * 4 + (l4 ^ (tk & 3))) * 16);
        s[0][nt] = MFMA16(qf[0][kk], kb, s[0][nt]);
        s[1][nt] = MFMA16(qf[1][kk], kb, s[1][nt]);
      }

    // online softmax (exp2 domain; scale folded into Q)
#pragma unroll
    for (int m = 0; m < 2; m++) {
#pragma unroll
      for (int rg = 0; rg < 4; rg++) {
        float mx = fmaxf(fmaxf(s[m][0][rg], s[m][1][rg]), fmaxf(s[m][2][rg], s[m][3][rg]));
        mx = fmaxf(mx, __shfl_xor(mx, 1));
        mx = fmaxf(mx, __shfl_xor(mx, 2));
        mx = fmaxf(mx, __shfl_xor(mx, 4));
        mx = fmaxf(mx, __shfl_xor(mx, 8));
        float mnew = fmaxf(mi_[m][rg], mx);
        float alpha = exp2f(mi_[m][rg] - mnew);
        float rs = 0.f;
#pragma unroll
        for (int nt = 0; nt < 4; nt++) {
          float p = exp2f(s[m][nt][rg] - mnew);
          s[m][nt][rg] = p;
          rs += p;
        }
        rs += __shfl_xor(rs, 1);
        rs += __shfl_xor(rs, 2);
        rs += __shfl_xor(rs, 4);
        rs += __shfl_xor(rs, 8);
        li_[m][rg] = li_[m][rg] * alpha + rs;
        mi_[m][rg] = mnew;
#pragma unroll
        for (int d5 = 0; d5 < 5; d5++) o[m][d5][rg] *= alpha;
      }
    }

    // P -> LDS (bf16, swizzled)
#pragma unroll
    for (int m = 0; m < 2; m++)
#pragma unroll
      for (int nt = 0; nt < 4; nt++)
#pragma unroll
        for (int rg = 0; rg < 4; rg++) {
          int r = m * 16 + l4 * 4 + rg;
          int col = nt * 16 + l15;
          *(u16*)((char*)pw + r * 128 + ((col >> 3) ^ (r & 7)) * 16 + (col & 7) * 2) =
              f2b(s[m][nt][rg]);
        }

    // PV
#pragma unroll
    for (int kk2 = 0; kk2 < 2; kk2++) {
      bf16x8 pa[2];
#pragma unroll
      for (int m = 0; m < 2; m++) {
        int r = m * 16 + l15;
        pa[m] = *(const bf16x8*)((const char*)pw + r * 128 + (((kk2 * 4 + l4) ^ (r & 7)) * 16));
      }
#pragma unroll
      for (int d5 = 0; d5 < 5; d5++) {
        int dd = d5 * 16 + l15;
        bf16x8 vb = *(const bf16x8*)((const char*)vls + dd * 128 + (((kk2 * 4 + l4) ^ (dd & 7)) * 16));
        o[0][d5] = MFMA16(pa[0], vb, o[0][d5]);
        o[1][d5] = MFMA16(pa[1], vb, o[1][d5]);
      }
    }
  }

  // epilogue: O / l -> Ob bf16
#pragma unroll
  for (int m = 0; m < 2; m++)
#pragma unroll
    for (int d5 = 0; d5 < 5; d5++)
#pragma unroll
      for (int rg = 0; rg < 4; rg++) {
        int r = b * N_ + q0 + m * 16 + l4 * 4 + rg;
        Ob[r * C_ + h * D_ + d5 * 16 + l15] = f2b(o[m][d5][rg] / li_[m][rg]);
      }
}

// ---------------- launch ----------------
extern "C" void kernel_launch(void* const* d_in, const int* in_sizes, int n_in,
                              void* d_out, int out_size, void* d_ws, size_t ws_size,
                              hipStream_t stream) {
  (void)in_sizes; (void)n_in; (void)out_size; (void)ws_size;
  const float* x    = (const float*)d_in[0];
  const float* Wq   = (const float*)d_in[1];
  const float* Wk   = (const float*)d_in[2];
  const float* Wv   = (const float*)d_in[3];
  const float* Wo   = (const float*)d_in[4];
  const float* bo   = (const float*)d_in[5];
  const float* mask = (const float*)d_in[6];

  // Workspace layout (peak 66,723,840 B). Ob aliases xb: xb's last reader
  // (k_gemm<0>, the Q projection) completes before k_attn writes Ob
  // (stream-ordered), so the overlap is safe and cuts peak ws by 13.1 MB.
  char* ws = (char*)d_ws;
  u16* xb  = (u16*)(ws + 0);          // 13,107,200
  u16* Ob  = xb;                      // alias (see above)
  u16* WqT = (u16*)(ws + 13107200);   //    819,200
  u16* WkT = (u16*)(ws + 13926400);
  u16* WvT = (u16*)(ws + 14745600);
  u16* WoT = (u16*)(ws + 15564800);
  u16* Qp  = (u16*)(ws + 16384000);   // 15,728,640
  u16* Kp  = (u16*)(ws + 32112640);   // 18,874,368
  u16* Vt  = (u16*)(ws + 50987008);   // 15,728,640
  int* sel = (int*)(ws + 66715648);   //      8,192

  k_convert_x<<<6400, 256, 0, stream>>>(x, xb);
  k_convert_w<<<dim3(20, 20, 4), 256, 0, stream>>>(Wq, Wk, Wv, Wo, WqT, WkT, WvT, WoT);
  k_scan<<<1, 1024, 0, stream>>>(mask, sel);
  k_padzero<<<640, 256, 0, stream>>>(Qp, Kp);
  k_gemm<1><<<dim3(80, 5), 256, 0, stream>>>(xb, WkT, Kp, nullptr);
  k_gemm<2><<<dim3(80, 5), 256, 0, stream>>>(xb, WvT, Vt, nullptr);
  k_gather<<<2048, 256, 0, stream>>>(sel, Kp, Vt);
  k_gemm<0><<<dim3(80, 5), 256, 0, stream>>>(xb, WqT, Qp, nullptr);
  k_attn<<<dim3(5, 8, 16), 256, 0, stream>>>(Qp, Kp, Vt, Ob);
  k_gemm<3><<<dim3(80, 5), 256, 0, stream>>>(Ob, WoT, d_out, bo);
}

// Round 3
// 307.509 us; speedup vs baseline: 1.3480x; 1.3480x over previous
//
#include <hip/hip_runtime.h>
#include <hip/hip_bf16.h>

#define B_    16
#define N_    640
#define C_    640
#define H_    8
#define D_    80
#define DP_   96          // padded head dim (3 x 32)
#define CP_   768         // H_*DP_
#define NSEL_ 2048
#define NTOK_ 10240       // B_*N_
#define NKV_  12288       // NTOK_+NSEL_

typedef short bf16x8 __attribute__((ext_vector_type(8)));
typedef float f32x4  __attribute__((ext_vector_type(4)));
typedef unsigned short u16;
typedef unsigned int   u32;

#define MFMA16(a,b,c) __builtin_amdgcn_mfma_f32_16x16x32_bf16((a),(b),(c),0,0,0)

// f32 -> bf16 round-to-nearest-even (finite inputs)
static __device__ __forceinline__ u16 f2b(float f) {
  u32 x = __builtin_bit_cast(u32, f);
  x += 0x7fffu + ((x >> 16) & 1u);
  return (u16)(x >> 16);
}
static __device__ __forceinline__ short f2bs(float f) {
  return (short)f2b(f);
}

// async global->LDS, 16B per lane
static __device__ __forceinline__ void gl16(const void* g, void* l) {
  __builtin_amdgcn_global_load_lds((const __attribute__((address_space(1))) u32*)g,
                                   (__attribute__((address_space(3))) u32*)l, 16, 0, 0);
}

// kv staging permutation: LDS K-row r holds token tokbase + PI(r).
// Chosen so swapped-QK^T output regs are exactly the PV A-fragment elements:
// PI(r) = 8*l4 + 32*(nt>>1) + 4*(nt&1) + rg  for r = nt*16 + l4*4 + rg.
static __device__ __forceinline__ int PI(int r) {
  return ((r >> 2) & 3) * 8 + (r >> 5) * 32 + ((r >> 4) & 1) * 4 + (r & 3);
}

// ---------------- convert x (f32 -> bf16), 4 elems/thread ----------------
__global__ __launch_bounds__(256) void k_convert_x(const float* __restrict__ x,
                                                   u16* __restrict__ xb) {
  int i = blockIdx.x * 256 + threadIdx.x;        // 1,638,400 threads
  float4 v = ((const float4*)x)[i];
  ushort4 o;
  o.x = f2b(v.x); o.y = f2b(v.y); o.z = f2b(v.z); o.w = f2b(v.w);
  ((ushort4*)xb)[i] = o;
}

// ---------------- convert W (f32 -> bf16 transposed) ----------------
__global__ __launch_bounds__(256) void k_convert_w(const float* w0, const float* w1,
                                                   const float* w2, const float* w3,
                                                   u16* t0, u16* t1, u16* t2, u16* t3) {
  const float* W = (blockIdx.z == 0) ? w0 : (blockIdx.z == 1) ? w1 : (blockIdx.z == 2) ? w2 : w3;
  u16*         T = (blockIdx.z == 0) ? t0 : (blockIdx.z == 1) ? t1 : (blockIdx.z == 2) ? t2 : t3;
  __shared__ float tile[32][33];
  int tx = threadIdx.x & 31, ty = threadIdx.x >> 5;   // 32 x 8
  int n0 = blockIdx.x * 32, k0 = blockIdx.y * 32;
#pragma unroll
  for (int r = 0; r < 4; r++)
    tile[ty + 8 * r][tx] = W[(k0 + ty + 8 * r) * C_ + n0 + tx];
  __syncthreads();
#pragma unroll
  for (int r = 0; r < 4; r++)
    T[(n0 + ty + 8 * r) * C_ + k0 + tx] = f2b(tile[tx][ty + 8 * r]);
}

// ---------------- zero the head-pad columns of Qp / Kp ----------------
__global__ __launch_bounds__(256) void k_padzero(u16* __restrict__ Qp, u16* __restrict__ Kp) {
  int i = blockIdx.x * 256 + threadIdx.x;   // 163840 jobs = 20480 rows * 8 heads
  int row = i >> 3, h = i & 7;
  u16* p = ((row < NTOK_) ? (Qp + row * CP_) : (Kp + (row - NTOK_) * CP_)) + h * DP_ + D_;
  uint4 z = {0u, 0u, 0u, 0u};
  *(uint4*)(p)     = z;
  *(uint4*)(p + 8) = z;
}

// ---------------- mask -> sel indices (order-preserving) ----------------
__global__ __launch_bounds__(1024) void k_scan(const float* __restrict__ mask,
                                               int* __restrict__ sel) {
  __shared__ int wcnt[16];
  __shared__ int carry;
  int tid = threadIdx.x, lane = tid & 63, wid = tid >> 6;
  float v[10];
#pragma unroll
  for (int r = 0; r < 10; r++) v[r] = mask[r * 1024 + tid];
  if (tid == 0) carry = 0;
  __syncthreads();
  for (int r = 0; r < 10; r++) {
    bool p = v[r] > 0.5f;
    unsigned long long b = __ballot(p);
    if (lane == 0) wcnt[wid] = __popcll(b);
    __syncthreads();
    int off = carry;
    for (int w = 0; w < wid; w++) off += wcnt[w];
    if (p) sel[off + __popcll(b & ((1ull << lane) - 1ull))] = r * 1024 + tid;
    __syncthreads();
    if (tid == 0) {
      int s = 0;
      for (int w = 0; w < 16; w++) s += wcnt[w];
      carry += s;
    }
    __syncthreads();
  }
}

// ---------------- GEMM: C[M,N] = A[M,640] * BT[N,640]^T ----------------
#define QSCALE_ (1.4426950408889634f * 0.11180339887498949f)

template <int MODE>
__global__ __launch_bounds__(256) void k_gemm(const u16* __restrict__ A,
                                              const u16* __restrict__ BT,
                                              void* __restrict__ out,
                                              const float* __restrict__ bias) {
  __shared__ u16 lA[128 * 32];
  __shared__ u16 lB[128 * 32];
  int tid = threadIdx.x, lane = tid & 63, wid = tid >> 6;
  int l15 = lane & 15, l4 = lane >> 4;
  int m0 = blockIdx.x * 128, n0 = blockIdx.y * 128;
  int wr = wid >> 1, wc = wid & 1;
  int tok = tid >> 2, ch = tid & 3;
  int sc = ch ^ (tok & 3);                 // pre-swizzled source chunk
  f32x4 acc[4][4];
#pragma unroll
  for (int mi = 0; mi < 4; mi++)
#pragma unroll
    for (int ni = 0; ni < 4; ni++) acc[mi][ni] = (f32x4){0.f, 0.f, 0.f, 0.f};

  for (int k0 = 0; k0 < C_; k0 += 32) {
    __syncthreads();
    gl16(A  + (m0 + tok)      * C_ + k0 + sc * 8, (char*)lA + tid * 16);
    gl16(A  + (m0 + tok + 64) * C_ + k0 + sc * 8, (char*)lA + 4096 + tid * 16);
    gl16(BT + (n0 + tok)      * C_ + k0 + sc * 8, (char*)lB + tid * 16);
    gl16(BT + (n0 + tok + 64) * C_ + k0 + sc * 8, (char*)lB + 4096 + tid * 16);
    __syncthreads();
    bf16x8 af[4], bfr[4];
#pragma unroll
    for (int mi = 0; mi < 4; mi++) {
      int r = wr * 64 + mi * 16 + l15;
      af[mi] = *(const bf16x8*)((const char*)lA + r * 64 + ((l4 ^ (r & 3)) * 16));
    }
#pragma unroll
    for (int ni = 0; ni < 4; ni++) {
      int r = wc * 64 + ni * 16 + l15;
      bfr[ni] = *(const bf16x8*)((const char*)lB + r * 64 + ((l4 ^ (r & 3)) * 16));
    }
#pragma unroll
    for (int mi = 0; mi < 4; mi++)
#pragma unroll
      for (int ni = 0; ni < 4; ni++) acc[mi][ni] = MFMA16(af[mi], bfr[ni], acc[mi][ni]);
  }

  int cbase = n0 + wc * 64, rbase = m0 + wr * 64;
  if (MODE == 0 || MODE == 1) {
    u16* P = (u16*)out;
#pragma unroll
    for (int mi = 0; mi < 4; mi++)
#pragma unroll
      for (int ni = 0; ni < 4; ni++) {
        int c = cbase + ni * 16 + l15;
        int h = c / 80, d = c % 80;
#pragma unroll
        for (int rg = 0; rg < 4; rg++) {
          int r = rbase + mi * 16 + l4 * 4 + rg;
          float v = acc[mi][ni][rg];
          if (MODE == 0) v *= QSCALE_;
          P[r * CP_ + h * DP_ + d] = f2b(v);
        }
      }
  } else if (MODE == 2) {
    u16* P = (u16*)out;
#pragma unroll
    for (int mi = 0; mi < 4; mi++)
#pragma unroll
      for (int ni = 0; ni < 4; ni++) {
        int c = cbase + ni * 16 + l15;
        int r0 = rbase + mi * 16 + l4 * 4;
        ushort4 pk;
        pk.x = f2b(acc[mi][ni][0]); pk.y = f2b(acc[mi][ni][1]);
        pk.z = f2b(acc[mi][ni][2]); pk.w = f2b(acc[mi][ni][3]);
        *(ushort4*)(P + c * NKV_ + r0) = pk;
      }
  } else {
    float* P = (float*)out;
#pragma unroll
    for (int ni = 0; ni < 4; ni++) {
      int c = cbase + ni * 16 + l15;
      float bv = bias[c];
#pragma unroll
      for (int mi = 0; mi < 4; mi++)
#pragma unroll
        for (int rg = 0; rg < 4; rg++)
          P[(rbase + mi * 16 + l4 * 4 + rg) * C_ + c] = acc[mi][ni][rg] + bv;
    }
  }
}

// ---------------- gather sel rows into Kp, sel cols into Vt ----------------
__global__ __launch_bounds__(256) void k_gather(const int* __restrict__ sel,
                                                u16* __restrict__ Kp,
                                                u16* __restrict__ Vt) {
  int i = blockIdx.x;            // 0..2047
  int t = threadIdx.x;
  int s = sel[i];
  const u32* src = (const u32*)(Kp + s * CP_);
  u32* dst = (u32*)(Kp + (NTOK_ + i) * CP_);
  dst[t] = src[t];
  if (t < 128) dst[256 + t] = src[256 + t];
  for (int c = t; c < C_; c += 256)
    Vt[c * NKV_ + NTOK_ + i] = Vt[c * NKV_ + s];
}

// ---------------- flash attention (v2) ----------------
// Swapped QK^T (A=K, B=Q) + PI-permuted K staging => softmax output regs ARE
// the PV A-fragments (no P LDS round-trip, no cross-lane exchange).
// Double-buffered K/V staging: issue tile t+1 loads, compute tile t, 1 barrier.
__global__ __launch_bounds__(256) void k_attn(const u16* __restrict__ Qp,
                                              const u16* __restrict__ Kp,
                                              const u16* __restrict__ Vt,
                                              u16* __restrict__ Ob) {
  __shared__ u16 kls[2][64 * DP_];          // 2 x 12,288 B
  __shared__ u16 vls[2][D_ * 64];           // 2 x 10,240 B
  __shared__ __align__(16) float als[4][2][16];  // per-wave alpha/li broadcast
  int tid = threadIdx.x, lane = tid & 63, wid = tid >> 6;
  int l15 = lane & 15, l4 = lane >> 4;
  int b = blockIdx.z, h = blockIdx.y, q0 = blockIdx.x * 128 + wid * 32;

  // Q fragments (pre-scaled by log2e/sqrt(d) in Qp); used as MFMA B-operand.
  bf16x8 qf[2][3];
#pragma unroll
  for (int m = 0; m < 2; m++)
#pragma unroll
    for (int kk = 0; kk < 3; kk++)
      qf[m][kk] = *(const bf16x8*)(Qp + (b * N_ + q0 + m * 16 + l15) * CP_ + h * DP_ + kk * 32 + l4 * 8);

  f32x4 o[2][5];
#pragma unroll
  for (int m = 0; m < 2; m++)
#pragma unroll
    for (int d5 = 0; d5 < 5; d5++) o[m][d5] = (f32x4){0.f, 0.f, 0.f, 0.f};
  float mi_[2] = {-1e30f, -1e30f}, li_[2] = {0.f, 0.f};

  // staging maps (constant per thread); K source row is PI-permuted.
  int i0 = tid, i1 = tid + 256, i2 = tid + 512;
  int kt0 = i0 / 12, kc0 = i0 % 12, ks0 = (kc0 & ~3) | ((kc0 & 3) ^ (kt0 & 3));
  int kt1 = i1 / 12, kc1 = i1 % 12, ks1 = (kc1 & ~3) | ((kc1 & 3) ^ (kt1 & 3));
  int kt2 = i2 / 12, kc2 = i2 % 12, ks2 = (kc2 & ~3) | ((kc2 & 3) ^ (kt2 & 3));
  int pk0 = PI(kt0), pk1 = PI(kt1), pk2 = PI(kt2);
  int vd0 = i0 >> 3, vs0 = (i0 & 7) ^ (vd0 & 7);
  int vd1 = i1 >> 3, vs1 = (i1 & 7) ^ (vd1 & 7);
  int vd2 = i2 >> 3, vs2 = (i2 & 7) ^ (vd2 & 7);

  auto stage = [&](int t, int buf) {
    int tokbase = (t < 10) ? (b * N_ + t * 64) : (NTOK_ + (t - 10) * 64);
    char* kd = (char*)kls[buf];
    char* vd = (char*)vls[buf];
    gl16(Kp + (tokbase + pk0) * CP_ + h * DP_ + ks0 * 8, kd + i0 * 16);
    gl16(Kp + (tokbase + pk1) * CP_ + h * DP_ + ks1 * 8, kd + i1 * 16);
    gl16(Kp + (tokbase + pk2) * CP_ + h * DP_ + ks2 * 8, kd + i2 * 16);
    gl16(Vt + (h * D_ + vd0) * NKV_ + tokbase + vs0 * 8, vd + i0 * 16);
    gl16(Vt + (h * D_ + vd1) * NKV_ + tokbase + vs1 * 8, vd + i1 * 16);
    if (tid < 128)
      gl16(Vt + (h * D_ + vd2) * NKV_ + tokbase + vs2 * 8, vd + i2 * 16);
  };

  stage(0, 0);
  __syncthreads();                 // compiler drains vmcnt before s_barrier
  int cur = 0;

  for (int t = 0; t < 42; t++) {
    if (t + 1 < 42) stage(t + 1, cur ^ 1);   // prefetch overlaps compute
    const char* klsc = (const char*)kls[cur];
    const char* vlsc = (const char*)vls[cur];

    // QK^T swapped: S^T[kv_row][q];  D col = q (l15), row = kv (l4*4+rg)
    f32x4 s[2][4];
#pragma unroll
    for (int m = 0; m < 2; m++)
#pragma unroll
      for (int nt = 0; nt < 4; nt++) s[m][nt] = (f32x4){0.f, 0.f, 0.f, 0.f};
#pragma unroll
    for (int kk = 0; kk < 3; kk++)
#pragma unroll
      for (int nt = 0; nt < 4; nt++) {
        int tk = nt * 16 + l15;
        bf16x8 kb = *(const bf16x8*)(klsc + tk * 192 + (kk * 4 + (l4 ^ (tk & 3))) * 16);
        s[0][nt] = MFMA16(kb, qf[0][kk], s[0][nt]);
        s[1][nt] = MFMA16(kb, qf[1][kk], s[1][nt]);
      }

    // row max (rows are l15-mapped; reduce in-lane then over l4 group)
    float rmax[2];
#pragma unroll
    for (int m = 0; m < 2; m++) {
      float t0 = fmaxf(fmaxf(s[m][0][0], s[m][0][1]), fmaxf(s[m][0][2], s[m][0][3]));
      float t1 = fmaxf(fmaxf(s[m][1][0], s[m][1][1]), fmaxf(s[m][1][2], s[m][1][3]));
      float t2 = fmaxf(fmaxf(s[m][2][0], s[m][2][1]), fmaxf(s[m][2][2], s[m][2][3]));
      float t3 = fmaxf(fmaxf(s[m][3][0], s[m][3][1]), fmaxf(s[m][3][2], s[m][3][3]));
      float mx = fmaxf(fmaxf(t0, t1), fmaxf(t2, t3));
      mx = fmaxf(mx, __shfl_xor(mx, 16));
      mx = fmaxf(mx, __shfl_xor(mx, 32));
      rmax[m] = mx;
    }

    // defer-max: skip rescale when max growth <= 8 (exp2 domain)
    int c = (rmax[0] - mi_[0] <= 8.f) && (rmax[1] - mi_[1] <= 8.f);
    if (!__all(c)) {
      float alpha[2];
#pragma unroll
      for (int m = 0; m < 2; m++) {
        float mnew = fmaxf(mi_[m], rmax[m]);
        alpha[m] = exp2f(mi_[m] - mnew);
        mi_[m] = mnew;
        li_[m] *= alpha[m];
      }
      if (l4 == 0) { als[wid][0][l15] = alpha[0]; als[wid][1][l15] = alpha[1]; }
      f32x4 a0 = *(const f32x4*)&als[wid][0][l4 * 4];
      f32x4 a1 = *(const f32x4*)&als[wid][1][l4 * 4];
#pragma unroll
      for (int d5 = 0; d5 < 5; d5++)
#pragma unroll
        for (int rg = 0; rg < 4; rg++) {
          o[0][d5][rg] *= a0[rg];
          o[1][d5][rg] *= a1[rg];
        }
    }

    // exp2 + row sum
#pragma unroll
    for (int m = 0; m < 2; m++) {
      float sum = 0.f;
#pragma unroll
      for (int nt = 0; nt < 4; nt++)
#pragma unroll
        for (int rg = 0; rg < 4; rg++) {
          float p = exp2f(s[m][nt][rg] - mi_[m]);
          s[m][nt][rg] = p;
          sum += p;
        }
      sum += __shfl_xor(sum, 16);
      sum += __shfl_xor(sum, 32);
      li_[m] += sum;
    }

    // pack P regs directly into PV A-fragments (PI makes this exact)
    bf16x8 pa[2][2];
#pragma unroll
    for (int m = 0; m < 2; m++)
#pragma unroll
      for (int kk2 = 0; kk2 < 2; kk2++) {
        bf16x8 w;
        w[0] = f2bs(s[m][2 * kk2][0]);     w[1] = f2bs(s[m][2 * kk2][1]);
        w[2] = f2bs(s[m][2 * kk2][2]);     w[3] = f2bs(s[m][2 * kk2][3]);
        w[4] = f2bs(s[m][2 * kk2 + 1][0]); w[5] = f2bs(s[m][2 * kk2 + 1][1]);
        w[6] = f2bs(s[m][2 * kk2 + 1][2]); w[7] = f2bs(s[m][2 * kk2 + 1][3]);
        pa[m][kk2] = w;
      }

    // PV: O[q][d] accum;  A=P (row=q), B=V (col=d)
#pragma unroll
    for (int kk2 = 0; kk2 < 2; kk2++)
#pragma unroll
      for (int d5 = 0; d5 < 5; d5++) {
        int dd = d5 * 16 + l15;
        bf16x8 vb = *(const bf16x8*)(vlsc + dd * 128 + (((kk2 * 4 + l4) ^ (dd & 7)) * 16));
        o[0][d5] = MFMA16(pa[0][kk2], vb, o[0][d5]);
        o[1][d5] = MFMA16(pa[1][kk2], vb, o[1][d5]);
      }

    __syncthreads();               // drains vmcnt: next buffer is ready
    cur ^= 1;
  }

  // epilogue: broadcast li (l15-mapped) to o-rows (l4-mapped), divide, store
  if (l4 == 0) { als[wid][0][l15] = li_[0]; als[wid][1][l15] = li_[1]; }
  f32x4 lb0 = *(const f32x4*)&als[wid][0][l4 * 4];
  f32x4 lb1 = *(const f32x4*)&als[wid][1][l4 * 4];
  float inv0[4], inv1[4];
#pragma unroll
  for (int rg = 0; rg < 4; rg++) { inv0[rg] = 1.f / lb0[rg]; inv1[rg] = 1.f / lb1[rg]; }
#pragma unroll
  for (int m = 0; m < 2; m++)
#pragma unroll
    for (int d5 = 0; d5 < 5; d5++)
#pragma unroll
      for (int rg = 0; rg < 4; rg++) {
        int r = b * N_ + q0 + m * 16 + l4 * 4 + rg;
        Ob[r * C_ + h * D_ + d5 * 16 + l15] = f2b(o[m][d5][rg] * (m ? inv1[rg] : inv0[rg]));
      }
}

// ---------------- launch ----------------
extern "C" void kernel_launch(void* const* d_in, const int* in_sizes, int n_in,
                              void* d_out, int out_size, void* d_ws, size_t ws_size,
                              hipStream_t stream) {
  (void)in_sizes; (void)n_in; (void)out_size; (void)ws_size;
  const float* x    = (const float*)d_in[0];
  const float* Wq   = (const float*)d_in[1];
  const float* Wk   = (const float*)d_in[2];
  const float* Wv   = (const float*)d_in[3];
  const float* Wo   = (const float*)d_in[4];
  const float* bo   = (const float*)d_in[5];
  const float* mask = (const float*)d_in[6];

  // Workspace layout (peak 66,723,840 B). Ob aliases xb: xb's last reader
  // (k_gemm<0>, the Q projection) completes before k_attn writes Ob.
  char* ws = (char*)d_ws;
  u16* xb  = (u16*)(ws + 0);          // 13,107,200
  u16* Ob  = xb;                      // alias (see above)
  u16* WqT = (u16*)(ws + 13107200);   //    819,200
  u16* WkT = (u16*)(ws + 13926400);
  u16* WvT = (u16*)(ws + 14745600);
  u16* WoT = (u16*)(ws + 15564800);
  u16* Qp  = (u16*)(ws + 16384000);   // 15,728,640
  u16* Kp  = (u16*)(ws + 32112640);   // 18,874,368
  u16* Vt  = (u16*)(ws + 50987008);   // 15,728,640
  int* sel = (int*)(ws + 66715648);   //      8,192

  k_convert_x<<<6400, 256, 0, stream>>>(x, xb);
  k_convert_w<<<dim3(20, 20, 4), 256, 0, stream>>>(Wq, Wk, Wv, Wo, WqT, WkT, WvT, WoT);
  k_scan<<<1, 1024, 0, stream>>>(mask, sel);
  k_padzero<<<640, 256, 0, stream>>>(Qp, Kp);
  k_gemm<1><<<dim3(80, 5), 256, 0, stream>>>(xb, WkT, Kp, nullptr);
  k_gemm<2><<<dim3(80, 5), 256, 0, stream>>>(xb, WvT, Vt, nullptr);
  k_gather<<<2048, 256, 0, stream>>>(sel, Kp, Vt);
  k_gemm<0><<<dim3(80, 5), 256, 0, stream>>>(xb, WqT, Qp, nullptr);
  k_attn<<<dim3(5, 8, 16), 256, 0, stream>>>(Qp, Kp, Vt, Ob);
  k_gemm<3><<<dim3(80, 5), 256, 0, stream>>>(Ob, WoT, d_out, bo);
}